// Round 3
// baseline (38.868 us; speedup 1.0000x reference)
//
#include <hip/hip_runtime.h>

#define NPTS 8192
#define KNN  15
#define QPW  4                // queries per wave
#define WPB  8                // waves per block
#define TPB  (WPB * 64)       // 512 threads

__device__ __forceinline__ int prefix_below(unsigned long long m) {
  return (int)__builtin_amdgcn_mbcnt_hi((unsigned int)(m >> 32),
            __builtin_amdgcn_mbcnt_lo((unsigned int)m, 0u));
}

// Ascending bitonic sort of one u32 per lane across a 64-lane wave.
__device__ __forceinline__ unsigned int bitonic_sort_u32(unsigned int v, int lane) {
#pragma unroll
  for (int k = 2; k <= 64; k <<= 1) {
#pragma unroll
    for (int j = k >> 1; j > 0; j >>= 1) {
      unsigned int o = __shfl_xor(v, j, 64);
      bool keep_min = ((lane & k) == 0) == ((lane & j) == 0);
      unsigned int lo = (v < o) ? v : o;
      unsigned int hi = (v < o) ? o : v;
      v = keep_min ? lo : hi;
    }
  }
  return v;
}

// Ascending bitonic sort of one u64 per lane across a 64-lane wave.
__device__ __forceinline__ unsigned long long bitonic_sort_u64(unsigned long long v, int lane) {
#pragma unroll
  for (int k = 2; k <= 64; k <<= 1) {
#pragma unroll
    for (int j = k >> 1; j > 0; j >>= 1) {
      unsigned long long o = __shfl_xor(v, j, 64);
      bool keep_min = ((lane & k) == 0) == ((lane & j) == 0);
      unsigned long long lo = (v < o) ? v : o;
      unsigned long long hi = (v < o) ? o : v;
      v = keep_min ? lo : hi;
    }
  }
  return v;
}

__global__ __launch_bounds__(TPB)
void knn_kernel(const float* __restrict__ x, const int* __restrict__ y,
                float* __restrict__ out) {
  __shared__ float4 sx4[NPTS / 2];                // 64 KB: all points, (x0,y0,x1,y1)
  __shared__ unsigned int ybits[NPTS / 32];       // 1 KB label bitset
  __shared__ unsigned int buf[WPB][QPW][64];      // 8 KB candidate-index buffers

  const int tid = threadIdx.x;

  // ---- stage x (coalesced float4) and y (bitset) into LDS ----
  const float4* gx4 = (const float4*)x;
#pragma unroll
  for (int i = tid; i < NPTS / 2; i += TPB) sx4[i] = gx4[i];
  if (tid < NPTS / 32) {
    const int4* yy = (const int4*)(y + (tid << 5));
    unsigned int b = 0;
#pragma unroll
    for (int k2 = 0; k2 < 8; ++k2) {
      int4 v = yy[k2];
      b |= ((unsigned int)(v.x & 1) << (4 * k2)) |
           ((unsigned int)(v.y & 1) << (4 * k2 + 1)) |
           ((unsigned int)(v.z & 1) << (4 * k2 + 2)) |
           ((unsigned int)(v.w & 1) << (4 * k2 + 3));
    }
    ybits[tid] = b;
  }
  __syncthreads();

  const int w = tid >> 6;
  const int lane = tid & 63;
  const int q0 = ((int)blockIdx.x * WPB + w) * QPW;   // this wave's four queries

  float qx[QPW], qy[QPW];
#pragma unroll
  for (int qi = 0; qi < QPW; ++qi) {
    float2 xq = ((const float2*)sx4)[q0 + qi];
    qx[qi] = xq.x; qy[qi] = xq.y;
  }

  // ---- pass 1: per-lane min distance per query (self NOT excluded) ----
  float m0[QPW], m1[QPW];
#pragma unroll
  for (int qi = 0; qi < QPW; ++qi) { m0[qi] = 3.0e38f; m1[qi] = 3.0e38f; }

#pragma unroll 8
  for (int s = 0; s < 64; ++s) {
    float4 p = sx4[(s << 6) + lane];
#pragma unroll
    for (int qi = 0; qi < QPW; ++qi) {
      float dx0 = qx[qi] - p.x, dy0 = qy[qi] - p.y;
      float dx1 = qx[qi] - p.z, dy1 = qy[qi] - p.w;
      float d0 = __builtin_fmaf(dx0, dx0, dy0 * dy0);
      float d1 = __builtin_fmaf(dx1, dx1, dy1 * dy1);
      m0[qi] = fminf(m0[qi], d0);
      m1[qi] = fminf(m1[qi], d1);
    }
  }

  // 16th-smallest lane-min (index KNN): 16 distinct candidates <= T, at most
  // one is self => >=15 non-self => T >= true 15th NN distance.
  float T[QPW];
#pragma unroll
  for (int qi = 0; qi < QPW; ++qi) {
    unsigned int s = bitonic_sort_u32(__float_as_uint(fminf(m0[qi], m1[qi])), lane);
    T[qi] = __uint_as_float(__shfl(s, KNN, 64)) * (1.0f + 1.0e-5f) + 1.0e-30f;
  }

  // ---- pass 2: compact indices of candidates with d32 <= T (incl. self) ----
  int cnt[QPW];
#pragma unroll
  for (int qi = 0; qi < QPW; ++qi) cnt[qi] = 0;

#pragma unroll 4
  for (int s = 0; s < 64; ++s) {
    float4 p = sx4[(s << 6) + lane];
    int j0 = ((s << 6) + lane) << 1;
#pragma unroll
    for (int qi = 0; qi < QPW; ++qi) {
      float dx0 = qx[qi] - p.x, dy0 = qy[qi] - p.y;
      float dx1 = qx[qi] - p.z, dy1 = qy[qi] - p.w;
      float d0 = __builtin_fmaf(dx0, dx0, dy0 * dy0);
      float d1 = __builtin_fmaf(dx1, dx1, dy1 * dy1);
      bool c0 = (d0 <= T[qi]);
      bool c1 = (d1 <= T[qi]);
      unsigned long long k0 = __ballot(c0);
      unsigned long long k1 = __ballot(c1);
      if (k0 | k1) {                       // wave-uniform, mostly not taken
        if (c0) {
          int o = cnt[qi] + prefix_below(k0);
          if (o < 64) buf[w][qi][o] = (unsigned)j0;
        }
        if (c1) {
          int o = cnt[qi] + __popcll(k0) + prefix_below(k1);
          if (o < 64) buf[w][qi][o] = (unsigned)(j0 + 1);
        }
        cnt[qi] += __popcll(k0) + __popcll(k1);   // wave-uniform register update
      }
    }
  }

  // ---- final: exact fp64 keys for the ~19 survivors, sort, vote ----
#pragma unroll
  for (int qi = 0; qi < QPW; ++qi) {
    const int q = q0 + qi;
    int C = cnt[qi];
    C = (C > 64) ? 64 : C;
    unsigned long long kv = ~0ull;
    if (lane < C) {
      int jj = (int)buf[w][qi][lane];
      float2 pj = ((const float2*)sx4)[jj];
      double dx = (double)qx[qi] - (double)pj.x;   // exact (fp32 -> fp64)
      double dy = (double)qy[qi] - (double)pj.y;
      double dd = dx * dx + dy * dy;               // rel err ~1e-16
      kv = ((unsigned long long)__double_as_longlong(dd) & ~0x1FFFull) |
           (unsigned long long)jj;                 // tie-break: lower index
      if (jj == q) kv = ~0ull;                     // drop self
    }
    kv = bitonic_sort_u64(kv, lane);
    int jj = (int)(kv & 0x1FFFull);
    int lbl = (int)((ybits[jj >> 5] >> (jj & 31)) & 1u);
    unsigned long long vm = __ballot((lane < KNN) && lbl);
    if (lane == 0) out[q] = (__popcll(vm) >= 8) ? 1.0f : 0.0f;   // sum > 7.5
  }
}

extern "C" void kernel_launch(void* const* d_in, const int* in_sizes, int n_in,
                              void* d_out, int out_size, void* d_ws, size_t ws_size,
                              hipStream_t stream) {
  const float* x = (const float*)d_in[0];
  const int* y = (const int*)d_in[1];
  float* out = (float*)d_out;
  dim3 grid(NPTS / (WPB * QPW));   // 256 blocks
  dim3 block(TPB);                 // 512 threads = 8 waves
  hipLaunchKernelGGL(knn_kernel, grid, block, 0, stream, x, y, out);
}

// Round 4
// 33.481 us; speedup vs baseline: 1.1609x; 1.1609x over previous
//
#include <hip/hip_runtime.h>

#define NPTS 8192
#define KNN  15
#define QPW  4       // queries per group
#define GPB  4       // groups per block (8 waves = 4 groups x 2 halves)
#define TPB  512
#define SEG  48      // per-half candidate buffer capacity

__device__ __forceinline__ int prefix_below(unsigned long long m) {
  return (int)__builtin_amdgcn_mbcnt_hi((unsigned int)(m >> 32),
            __builtin_amdgcn_mbcnt_lo((unsigned int)m, 0u));
}

// Ascending bitonic sort of one u32 per lane across a 64-lane wave.
__device__ __forceinline__ unsigned int bitonic_sort_u32(unsigned int v, int lane) {
#pragma unroll
  for (int k = 2; k <= 64; k <<= 1) {
#pragma unroll
    for (int j = k >> 1; j > 0; j >>= 1) {
      unsigned int o = __shfl_xor(v, j, 64);
      bool keep_min = ((lane & k) == 0) == ((lane & j) == 0);
      unsigned int lo = (v < o) ? v : o;
      unsigned int hi = (v < o) ? o : v;
      v = keep_min ? lo : hi;
    }
  }
  return v;
}

// Ascending bitonic sort of one u64 per lane across a 64-lane wave.
__device__ __forceinline__ unsigned long long bitonic_sort_u64(unsigned long long v, int lane) {
#pragma unroll
  for (int k = 2; k <= 64; k <<= 1) {
#pragma unroll
    for (int j = k >> 1; j > 0; j >>= 1) {
      unsigned long long o = __shfl_xor(v, j, 64);
      bool keep_min = ((lane & k) == 0) == ((lane & j) == 0);
      unsigned long long lo = (v < o) ? v : o;
      unsigned long long hi = (v < o) ? o : v;
      v = keep_min ? lo : hi;
    }
  }
  return v;
}

__global__ __launch_bounds__(TPB)
void knn_kernel(const float* __restrict__ x, const int* __restrict__ y,
                float* __restrict__ out) {
  __shared__ float4 sx4[NPTS / 2];                 // 64 KB: all points
  __shared__ unsigned int ybits[NPTS / 32];        // 1 KB label bitset
  __shared__ float tmin[GPB][QPW][2][16];          // 2 KB: per-half sorted 16-smallest lane-mins
  __shared__ unsigned int buf[GPB][QPW][2][SEG];   // 6 KB candidate indices (per-half segments)
  __shared__ int cntl[GPB][QPW][2];                // counts

  const int tid = threadIdx.x;

  // ---- stage x (coalesced float4) and y (bitset) into LDS ----
  const float4* gx4 = (const float4*)x;
#pragma unroll
  for (int i = tid; i < NPTS / 2; i += TPB) sx4[i] = gx4[i];
  if (tid < NPTS / 32) {
    const int4* yy = (const int4*)(y + (tid << 5));
    unsigned int b = 0;
#pragma unroll
    for (int k2 = 0; k2 < 8; ++k2) {
      int4 v = yy[k2];
      b |= ((unsigned int)(v.x & 1) << (4 * k2)) |
           ((unsigned int)(v.y & 1) << (4 * k2 + 1)) |
           ((unsigned int)(v.z & 1) << (4 * k2 + 2)) |
           ((unsigned int)(v.w & 1) << (4 * k2 + 3));
    }
    ybits[tid] = b;
  }
  __syncthreads();

  const int w = tid >> 6;
  const int lane = tid & 63;
  const int g = w & 3;        // query group
  const int h = w >> 2;       // point half
  const int qbase = (int)blockIdx.x * (GPB * QPW) + g * QPW;

  float qx[QPW], qy[QPW];
#pragma unroll
  for (int qi = 0; qi < QPW; ++qi) {
    float2 xq = ((const float2*)sx4)[qbase + qi];
    qx[qi] = xq.x; qy[qi] = xq.y;
  }

  const float4* base = sx4 + h * (NPTS / 4);   // this wave's 4096-point half

  // ---- pass 1: per-lane min over this half's 64-point stripe, per query ----
  float m[QPW];
#pragma unroll
  for (int qi = 0; qi < QPW; ++qi) m[qi] = 3.0e38f;

#pragma unroll 8
  for (int s = 0; s < 32; ++s) {
    float4 p = base[(s << 6) + lane];
#pragma unroll
    for (int qi = 0; qi < QPW; ++qi) {
      float dx0 = qx[qi] - p.x, dy0 = qy[qi] - p.y;
      float dx1 = qx[qi] - p.z, dy1 = qy[qi] - p.w;
      float d0 = __builtin_fmaf(dx0, dx0, dy0 * dy0);
      float d1 = __builtin_fmaf(dx1, dx1, dy1 * dy1);
      m[qi] = fminf(fminf(d0, d1), m[qi]);       // v_min3 candidate
    }
  }

  // publish each half's sorted 16 smallest lane-mins
#pragma unroll
  for (int qi = 0; qi < QPW; ++qi) {
    unsigned int srt = bitonic_sort_u32(__float_as_uint(m[qi]), lane);
    if (lane < 16) tmin[g][qi][h][lane] = __uint_as_float(srt);
  }
  __syncthreads();

  // ---- threshold: 16th smallest of the union of the two sorted 16-lists ----
  // merged[15] = min over i in [0,16] of max(A[i-1], B[15-i]); distances >= 0
  // so the out-of-range sentinel can be 0. 16 distinct points <= T, at most
  // one self => >=15 non-self => T >= true 15th-NN distance.
  float T[QPW];
#pragma unroll
  for (int qi = 0; qi < QPW; ++qi) {
    float cand = 3.0e38f;
    if (lane <= 16) {
      float a = (lane == 0) ? 0.0f : tmin[g][qi][0][lane - 1];
      float b = (lane == 16) ? 0.0f : tmin[g][qi][1][15 - lane];
      cand = fmaxf(a, b);
    }
#pragma unroll
    for (int j = 32; j >= 1; j >>= 1) cand = fminf(cand, __shfl_xor(cand, j, 64));
    T[qi] = cand * (1.0f + 1.0e-5f) + 1.0e-30f;  // margin >> fp32 eval noise
  }

  // ---- pass 2: compact indices with d32 <= T into this half's segment ----
  int cnt[QPW];
#pragma unroll
  for (int qi = 0; qi < QPW; ++qi) cnt[qi] = 0;

#pragma unroll 4
  for (int s = 0; s < 32; ++s) {
    float4 p = base[(s << 6) + lane];
    int j0 = (h * (NPTS / 4) + (s << 6) + lane) << 1;
#pragma unroll
    for (int qi = 0; qi < QPW; ++qi) {
      float dx0 = qx[qi] - p.x, dy0 = qy[qi] - p.y;
      float dx1 = qx[qi] - p.z, dy1 = qy[qi] - p.w;
      float d0 = __builtin_fmaf(dx0, dx0, dy0 * dy0);
      float d1 = __builtin_fmaf(dx1, dx1, dy1 * dy1);
      bool c0 = (d0 <= T[qi]);
      bool c1 = (d1 <= T[qi]);
      unsigned long long k0 = __ballot(c0);
      unsigned long long k1 = __ballot(c1);
      if (k0 | k1) {                             // wave-uniform, rarely taken
        if (c0) {
          int o = cnt[qi] + prefix_below(k0);
          if (o < SEG) buf[g][qi][h][o] = (unsigned)j0;
        }
        if (c1) {
          int o = cnt[qi] + __popcll(k0) + prefix_below(k1);
          if (o < SEG) buf[g][qi][h][o] = (unsigned)(j0 + 1);
        }
        cnt[qi] += __popcll(k0) + __popcll(k1);
      }
    }
  }
  if (lane == 0) {
    cntl[g][0][h] = cnt[0]; cntl[g][1][h] = cnt[1];
    cntl[g][2][h] = cnt[2]; cntl[g][3][h] = cnt[3];
  }
  __syncthreads();

  // ---- final: each wave finishes 2 of its group's queries ----
#pragma unroll
  for (int t = 0; t < 2; ++t) {
    const int ql = 2 * h + t;
    const int q = qbase + ql;
    const float2 xq = ((const float2*)sx4)[q];
    int C0 = cntl[g][ql][0]; C0 = (C0 > SEG) ? SEG : C0;
    int C1 = cntl[g][ql][1]; C1 = (C1 > SEG) ? SEG : C1;
    int Ct = C0 + C1; Ct = (Ct > 64) ? 64 : Ct;
    unsigned long long kv = ~0ull;
    if (lane < Ct) {
      int jj = (lane < C0) ? (int)buf[g][ql][0][lane]
                           : (int)buf[g][ql][1][lane - C0];
      float2 pj = ((const float2*)sx4)[jj];
      double dx = (double)xq.x - (double)pj.x;   // exact (fp32 -> fp64)
      double dy = (double)xq.y - (double)pj.y;
      double dd = dx * dx + dy * dy;             // rel err ~1e-16
      kv = ((unsigned long long)__double_as_longlong(dd) & ~0x1FFFull) |
           (unsigned long long)jj;               // tie-break: lower index
      if (jj == q) kv = ~0ull;                   // drop self
    }
    kv = bitonic_sort_u64(kv, lane);
    int jj = (int)(kv & 0x1FFFull);
    int lbl = (int)((ybits[jj >> 5] >> (jj & 31)) & 1u);
    unsigned long long vm = __ballot((lane < KNN) && lbl);
    if (lane == 0) out[q] = (__popcll(vm) >= 8) ? 1.0f : 0.0f;   // sum > 7.5
  }
}

extern "C" void kernel_launch(void* const* d_in, const int* in_sizes, int n_in,
                              void* d_out, int out_size, void* d_ws, size_t ws_size,
                              hipStream_t stream) {
  const float* x = (const float*)d_in[0];
  const int* y = (const int*)d_in[1];
  float* out = (float*)d_out;
  dim3 grid(NPTS / (GPB * QPW));   // 512 blocks
  dim3 block(TPB);                 // 512 threads = 8 waves
  hipLaunchKernelGGL(knn_kernel, grid, block, 0, stream, x, y, out);
}

// Round 6
// 31.888 us; speedup vs baseline: 1.2189x; 1.0499x over previous
//
#include <hip/hip_runtime.h>
#include <hip/hip_fp16.h>

#define NPTS 8192
#define KNN  15
#define WPB  8                // waves per block, 1 query per wave
#define TPB  (WPB * 64)       // 512 threads
#define SEG  64               // candidate buffer capacity per query

__device__ __forceinline__ int prefix_below(unsigned long long m) {
  return (int)__builtin_amdgcn_mbcnt_hi((unsigned int)(m >> 32),
            __builtin_amdgcn_mbcnt_lo((unsigned int)m, 0u));
}

// Packed fp16 min (ROCm header lacks __hmin2): single v_pk_min_f16.
__device__ __forceinline__ __half2 hmin2(__half2 a, __half2 b) {
  __half2 r;
  asm("v_pk_min_f16 %0, %1, %2" : "=v"(r) : "v"(a), "v"(b));
  return r;
}

// Ascending bitonic sort of one u32 per lane across a 64-lane wave.
__device__ __forceinline__ unsigned int bitonic_sort_u32(unsigned int v, int lane) {
#pragma unroll
  for (int k = 2; k <= 64; k <<= 1) {
#pragma unroll
    for (int j = k >> 1; j > 0; j >>= 1) {
      unsigned int o = __shfl_xor(v, j, 64);
      bool keep_min = ((lane & k) == 0) == ((lane & j) == 0);
      unsigned int lo = (v < o) ? v : o;
      unsigned int hi = (v < o) ? o : v;
      v = keep_min ? lo : hi;
    }
  }
  return v;
}

// Ascending bitonic sort of one u64 per lane across a 64-lane wave.
__device__ __forceinline__ unsigned long long bitonic_sort_u64(unsigned long long v, int lane) {
#pragma unroll
  for (int k = 2; k <= 64; k <<= 1) {
#pragma unroll
    for (int j = k >> 1; j > 0; j >>= 1) {
      unsigned long long o = __shfl_xor(v, j, 64);
      bool keep_min = ((lane & k) == 0) == ((lane & j) == 0);
      unsigned long long lo = (v < o) ? v : o;
      unsigned long long hi = (v < o) ? o : v;
      v = keep_min ? lo : hi;
    }
  }
  return v;
}

__global__ __launch_bounds__(TPB, 8)   // cap VGPR at 64 -> 8 waves/SIMD
void knn_kernel(const float* __restrict__ x, const int* __restrict__ y,
                float* __restrict__ out) {
  // sp layout: uint4 j = (xpair, ypair, xpair, ypair) covering points 4j..4j+3,
  // each pair is packed half2 of two consecutive points' coords.
  __shared__ __align__(16) unsigned int sp[NPTS];   // 32 KB fp16 screening copy
  __shared__ unsigned int ybits[NPTS / 32];         // 1 KB label bitset
  __shared__ unsigned int buf[WPB][SEG];            // 2 KB candidate indices

  const int tid = threadIdx.x;

  // ---- stage fp16-packed points and label bitset ----
  const float4* gx4 = (const float4*)x;             // pairs of points
#pragma unroll
  for (int i = tid; i < NPTS / 2; i += TPB) {
    float4 p = gx4[i];
    __half2 hx = __floats2half2_rn(p.x, p.z);
    __half2 hy = __floats2half2_rn(p.y, p.w);
    sp[2 * i]     = *(const unsigned int*)&hx;
    sp[2 * i + 1] = *(const unsigned int*)&hy;
  }
  if (tid < NPTS / 32) {
    const int4* yy = (const int4*)(y + (tid << 5));
    unsigned int b = 0;
#pragma unroll
    for (int k2 = 0; k2 < 8; ++k2) {
      int4 v = yy[k2];
      b |= ((unsigned int)(v.x & 1) << (4 * k2)) |
           ((unsigned int)(v.y & 1) << (4 * k2 + 1)) |
           ((unsigned int)(v.z & 1) << (4 * k2 + 2)) |
           ((unsigned int)(v.w & 1) << (4 * k2 + 3));
    }
    ybits[tid] = b;
  }
  __syncthreads();   // the only barrier; waves are independent below

  const int w = tid >> 6;
  const int lane = tid & 63;
  const int q = (int)blockIdx.x * WPB + w;
  const float2 xq = ((const float2*)x)[q];          // exact fp32 query coords
  const __half2 qx2 = __floats2half2_rn(xq.x, xq.x);  // same rounding as staged
  const __half2 qy2 = __floats2half2_rn(xq.y, xq.y);

  const uint4* sp4 = (const uint4*)sp;

  // ---- pass 1: per-lane fp16 min over 128-point stripe (self included, d=0) ----
  __half2 mm = __floats2half2_rn(6.0e4f, 6.0e4f);
#pragma unroll 4
  for (int s = 0; s < 32; ++s) {
    uint4 v = sp4[(s << 6) + lane];
    __half2 xa = *(const __half2*)&v.x, ya = *(const __half2*)&v.y;
    __half2 xb = *(const __half2*)&v.z, yb = *(const __half2*)&v.w;
    __half2 dxa = __hsub2(xa, qx2), dya = __hsub2(ya, qy2);
    __half2 dxb = __hsub2(xb, qx2), dyb = __hsub2(yb, qy2);
    __half2 da = __hfma2(dxa, dxa, __hmul2(dya, dya));
    __half2 db = __hfma2(dxb, dxb, __hmul2(dyb, dyb));
    mm = hmin2(mm, hmin2(da, db));
  }
  float m = fminf(__low2float(mm), __high2float(mm));

  // 16th-smallest lane-min: >=16 distinct points with fp16 d <= T, at most one
  // self => T upper-bounds the fp16 d of the true 16th point.
  unsigned int srt = bitonic_sort_u32(__float_as_uint(m), lane);
  const float T = __uint_as_float(__shfl(srt, KNN, 64));
  // Margin covering fp16<->fp64 discrepancy both ways (coord rounding ~2e-3 abs,
  // |dd| <= 2*e*(|dx|+|dy|) + e^2 + ulp terms), ~2x headroom:
  const float M = 0.035f * sqrtf(T) + 2.0e-4f + 0.01f * T;
  __half hTf = __float2half_rn(T + M);
  hTf = __ushort_as_half((unsigned short)(__half_as_ushort(hTf) + 2)); // round up 2 ulp
  const float Tff = __half2float(hTf);     // exact value of the fp16 threshold
  const __half2 Tf2 = __half2half2(hTf);

  // ---- pass 2: collect indices with fp16 d <= Tf (bit-identical d to pass 1) ----
  int cnt = 0;
#pragma unroll 2
  for (int s = 0; s < 32; ++s) {
    uint4 v = sp4[(s << 6) + lane];
    __half2 xa = *(const __half2*)&v.x, ya = *(const __half2*)&v.y;
    __half2 xb = *(const __half2*)&v.z, yb = *(const __half2*)&v.w;
    __half2 dxa = __hsub2(xa, qx2), dya = __hsub2(ya, qy2);
    __half2 dxb = __hsub2(xb, qx2), dyb = __hsub2(yb, qy2);
    __half2 da = __hfma2(dxa, dxa, __hmul2(dya, dya));
    __half2 db = __hfma2(dxb, dxb, __hmul2(dyb, dyb));
    __half2 ta = __hsub2(Tf2, da);                 // sign clear <=> candidate
    __half2 tb = __hsub2(Tf2, db);
    unsigned int sgn = (*(const unsigned int*)&ta) &
                       (*(const unsigned int*)&tb) & 0x80008000u;
    if (__any(sgn != 0x80008000u)) {               // any of 256 pts is a candidate
      int jb = ((s << 6) + lane) << 2;
      float d0 = __low2float(da), d1 = __high2float(da);
      float d2 = __low2float(db), d3 = __high2float(db);
      bool c0 = d0 <= Tff, c1 = d1 <= Tff, c2 = d2 <= Tff, c3 = d3 <= Tff;
      unsigned long long k0 = __ballot(c0);
      if (c0) { int o = cnt + prefix_below(k0); if (o < SEG) buf[w][o] = jb; }
      cnt += __popcll(k0);
      unsigned long long k1 = __ballot(c1);
      if (c1) { int o = cnt + prefix_below(k1); if (o < SEG) buf[w][o] = jb + 1; }
      cnt += __popcll(k1);
      unsigned long long k2 = __ballot(c2);
      if (c2) { int o = cnt + prefix_below(k2); if (o < SEG) buf[w][o] = jb + 2; }
      cnt += __popcll(k2);
      unsigned long long k3 = __ballot(c3);
      if (c3) { int o = cnt + prefix_below(k3); if (o < SEG) buf[w][o] = jb + 3; }
      cnt += __popcll(k3);
    }
  }

  // ---- final: exact fp64 keys from original fp32 coords, sort, vote ----
  int C = (cnt > SEG) ? SEG : cnt;                 // expected ~26, >=16 certified
  unsigned long long kv = ~0ull;
  if (lane < C) {
    int jj = (int)buf[w][lane];
    float2 pj = ((const float2*)x)[jj];
    double dx = (double)xq.x - (double)pj.x;       // exact fp32->fp64
    double dy = (double)xq.y - (double)pj.y;
    double dd = dx * dx + dy * dy;                 // rel err ~1e-16
    kv = ((unsigned long long)__double_as_longlong(dd) & ~0x1FFFull) |
         (unsigned long long)jj;                   // tie-break: lower index
    if (jj == q) kv = ~0ull;                       // drop self
  }
  kv = bitonic_sort_u64(kv, lane);
  int j15 = (int)(kv & 0x1FFFull);
  int lbl = (int)((ybits[j15 >> 5] >> (j15 & 31)) & 1u);
  unsigned long long vm = __ballot((lane < KNN) && lbl);
  if (lane == 0) out[q] = (__popcll(vm) >= 8) ? 1.0f : 0.0f;   // sum > 7.5
}

extern "C" void kernel_launch(void* const* d_in, const int* in_sizes, int n_in,
                              void* d_out, int out_size, void* d_ws, size_t ws_size,
                              hipStream_t stream) {
  const float* x = (const float*)d_in[0];
  const int* y = (const int*)d_in[1];
  float* out = (float*)d_out;
  dim3 grid(NPTS / WPB);   // 1024 blocks x 8 waves = 8192 waves (1 query each)
  dim3 block(TPB);
  hipLaunchKernelGGL(knn_kernel, grid, block, 0, stream, x, y, out);
}